// Round 7
// baseline (5579.713 us; speedup 1.0000x reference)
//
#include <hip/hip_runtime.h>
#include <math.h>

// ConvLSTM encoder, MI355X. Batch-persistent: one block per batch element,
// 256 threads (4 waves). All recurrent state on-chip: h0/h1 bf16 in LDS,
// c0/c1 fp32 in registers. Convs = MFMA GEMMs (M=pixels, N=gates*ch,
// K=im2col taps read straight from LDS h-state).
// R2-R6 lesson: the register allocator ALWAYS budgets VGPRs for 2 blocks/CU
// (VGPR cap = 1024/waves_per_block, attributes & LDS ignored). So: 4-wave
// blocks (cap 256) + per-lane demand designed to ~235: layer-1 in 2 M-passes
// (acc 96), pass-0 h staged in LDS not regs, addresses recomputed per pass,
// no B prefetch double-buffer, unroll-1 K-loops.

typedef __bf16 bf16x8 __attribute__((ext_vector_type(8)));
typedef float  f32x4  __attribute__((ext_vector_type(4)));

__device__ __forceinline__ float sigm(float x)  { return 1.f / (1.f + __expf(-x)); }
__device__ __forceinline__ float ftanh(float x) { float e = __expf(2.f * x); return 1.f - 2.f / (e + 1.f); }

// ---------------- workspace layout (bytes) ----------------
#define OFF_WP0  ((size_t)0)          // [128][320] bf16 = 81,920
#define OFF_WP1  ((size_t)81920)      // [256][864] bf16 = 442,368
#define OFF_WFC  ((size_t)524288)     // [168][64][64] bf16 = 1,376,256
#define WS_NEED  ((size_t)1900544)

// ---------------- weight pack kernels ----------------
// Wp0[n][k], n=gate*32+ch (128 rows), K=320: k<32 = im2col-x (ky*6+kx*2+cin,
// zero-padded 18->32); k>=32: (tap*32+c) from Wh0[n][c][tap].
__global__ void pack_w0(const float* __restrict__ wx0, const float* __restrict__ wh0,
                        __bf16* __restrict__ dst) {
  int o = blockIdx.x * 256 + threadIdx.x;
  if (o >= 128 * 320) return;
  int n = o / 320, k = o - n * 320;
  float v = 0.f;
  if (k < 32) {
    if (k < 18) {
      int ky = k / 6, rem = k - ky * 6, kx = rem >> 1, ci = rem & 1;
      v = wx0[(n * 2 + ci) * 9 + ky * 3 + kx];
    }
  } else {
    int tk = k - 32, tap = tk >> 5, c = tk & 31;
    v = wh0[(n * 32 + c) * 9 + tap];
  }
  dst[o] = (__bf16)v;
}

// Wp1[n][k], n=gate*64+ch (256 rows), K=864: k<288: tap*32+c from Wx1 (cin=32);
// k>=288: ((tap*2+half)*32+c) from Wh1[n][half*32+c][tap] (cin=64).
__global__ void pack_w1(const float* __restrict__ wx1, const float* __restrict__ wh1,
                        __bf16* __restrict__ dst) {
  int o = blockIdx.x * 256 + threadIdx.x;
  if (o >= 256 * 864) return;
  int n = o / 864, k = o - n * 864;
  float v;
  if (k < 288) {
    int tap = k >> 5, c = k & 31;
    v = wx1[(n * 32 + c) * 9 + tap];
  } else {
    int tk = k - 288, s2 = tk >> 5, c = tk & 31, tap = s2 >> 1, hf = s2 & 1;
    v = wh1[(n * 64 + hf * 32 + c) * 9 + tap];
  }
  dst[o] = (__bf16)v;
}

// Wfc2[pix][ch][n] bf16 = fc1_w[n][ch*168+pix]
__global__ void pack_wfc(const float* __restrict__ w, __bf16* __restrict__ dst) {
  int o = blockIdx.x * 256 + threadIdx.x;
  if (o >= 168 * 64 * 64) return;
  int pix = o >> 12, ch = (o >> 6) & 63, n = o & 63;
  dst[o] = (__bf16)w[n * 10752 + ch * 168 + pix];
}

// ---------------- the persistent ConvLSTM kernel ----------------
__global__ __launch_bounds__(256) void convlstm_persistent(
    const float* __restrict__ input, const float* __restrict__ x_ex,
    const __bf16* __restrict__ wp0, const __bf16* __restrict__ wp1,
    const __bf16* __restrict__ wfc2,
    const float* __restrict__ bx0, const float* __restrict__ bx1,
    const float* __restrict__ wc0, const float* __restrict__ wc1,
    const float* __restrict__ fc1b,
    const float* __restrict__ exw, const float* __restrict__ exb,
    float* __restrict__ out)
{
  __shared__ __bf16 sh0[9 * 26 * 40];    // h0 padded [y][x][40]  (18,720 B)
  __shared__ __bf16 sh1[9 * 26 * 72];    // h1 padded [y][x][72]  (33,696 B)
  __shared__ __bf16 sx2[168 * 32];       // im2col x, swizzled    (10,752 B)
  __shared__ __bf16 sstage[96 * 64];     // l1 pass-0 h staging   (12,288 B)
  // total 75,456 B -> 2 blocks/CU fit (matches allocator's 2-block budget)

  const int b = blockIdx.x;
  const int t = threadIdx.x;
  const int w = t >> 6, L = t & 63;
  const int lo16 = L & 15, hi4 = L >> 4;

  // ---- zero LDS (sstage needs no init) ----
  {
    int* p0 = (int*)sh0;
    for (int i = t; i < 9 * 26 * 40 / 2; i += 256) p0[i] = 0;
    int* p1 = (int*)sh1;
    for (int i = t; i < 9 * 26 * 72 / 2; i += 256) p1[i] = 0;
    int* p2 = (int*)sx2;
    for (int i = t; i < 168 * 32 / 2; i += 256) p2[i] = 0;
  }
  __syncthreads();

  // ---- build im2col x2 (time-constant), k-chunk XOR-swizzled per pixel ----
  if (t < 168) {
    int iy = t / 24, ix = t - iy * 24;
    int key = (t >> 1) & 3;
    __bf16* dst = sx2 + t * 32;
    for (int ky = 0; ky < 3; ++ky) {
      int y = iy + ky - 1;
      if (y < 0 || y >= 7) continue;
      for (int kx = 0; kx < 3; ++kx) {
        int x = ix + kx - 1;
        if (x < 0 || x >= 24) continue;
        int k0 = ky * 6 + kx * 2;
        dst[(((k0 + 0) >> 3) ^ key) * 8 + ((k0 + 0) & 7)] =
            (__bf16)input[((b * 2 + 0) * 7 + y) * 24 + x];
        dst[(((k0 + 1) >> 3) ^ key) * 8 + ((k0 + 1) & 7)] =
            (__bf16)input[((b * 2 + 1) * 7 + y) * 24 + x];
      }
    }
  }

  // ---- per-wave / per-lane constants ----
  // layer 0: wave = (mh 0..1) x (chh 0..1): M-tiles mh*6+j (6 / 5 real), 16 ch
  // layer 1: wave = chq (0..3), 16 ch; 2 M-passes: tiles p01*6+j (6 / 5 real)
  const int mh = w >> 1, chh = w & 1;
  const int chq = w;
  const int nt0 = (mh == 1) ? 5 : 6;

  int b0h[6];
#pragma unroll
  for (int j = 0; j < 6; ++j) {
    int pr = (mh * 6 + j) * 16 + lo16;
    if (pr > 167) pr = 167;            // dummy rows clamp (masked in epilogue)
    int iy = pr / 24, ix = pr - iy * 24;
    b0h[j] = (iy * 26 + ix) * 40;
  }
  const int ch0 = chh * 16 + lo16;     // layer-0 channel (0..31)
  const int ch1 = chq * 16 + lo16;     // layer-1 channel (0..63)

  const __bf16* w0base = wp0 + (size_t)ch0 * 320 + hi4 * 8;   // + g*10240
  const __bf16* w1base = wp1 + (size_t)ch1 * 864 + hi4 * 8;   // + g*55296

  float c0r[6][4], c1rA[6][4], c1rB[6][4];
#pragma unroll
  for (int j = 0; j < 6; ++j)
#pragma unroll
    for (int r = 0; r < 4; ++r) { c0r[j][r] = 0.f; c1rA[j][r] = 0.f; c1rB[j][r] = 0.f; }

  __syncthreads();   // x2 + zeroed state visible

#pragma unroll 1
  for (int st = 0; st < 7; ++st) {
    // ================= layer 0 (all 4 waves) =================
    {
      f32x4 a0[4][6];
#pragma unroll
      for (int g = 0; g < 4; ++g)
#pragma unroll
        for (int j = 0; j < 6; ++j) a0[g][j] = (f32x4){0.f, 0.f, 0.f, 0.f};

      // s = 0: time-constant x chunk (swizzled)
      {
        bf16x8 bc[4];
#pragma unroll
        for (int g = 0; g < 4; ++g) bc[g] = *(const bf16x8*)(w0base + g * 10240);
#pragma unroll
        for (int j = 0; j < 6; ++j) {
          if (j < nt0) {
            int pr = (mh * 6 + j) * 16 + lo16;
            if (pr > 167) pr = 167;
            bf16x8 af = *(const bf16x8*)(sx2 + pr * 32 + ((hi4 ^ ((pr >> 1) & 3)) * 8));
#pragma unroll
            for (int g = 0; g < 4; ++g)
              a0[g][j] = __builtin_amdgcn_mfma_f32_16x16x32_bf16(af, bc[g], a0[g][j], 0, 0, 0);
          }
        }
      }
#pragma unroll 1
      for (int s = 1; s < 10; ++s) {
        bf16x8 bc[4];
#pragma unroll
        for (int g = 0; g < 4; ++g)
          bc[g] = *(const bf16x8*)(w0base + g * 10240 + s * 32);
        int tap = s - 1, ky = tap / 3, kx = tap - ky * 3;
        int toff = (ky * 26 + kx) * 40 + hi4 * 8;
#pragma unroll
        for (int j = 0; j < 6; ++j) {
          if (j < nt0) {
            bf16x8 af = *(const bf16x8*)(sh0 + b0h[j] + toff);
#pragma unroll
            for (int g = 0; g < 4; ++g)
              a0[g][j] = __builtin_amdgcn_mfma_f32_16x16x32_bf16(af, bc[g], a0[g][j], 0, 0, 0);
          }
        }
      }
      __syncthreads();   // all h0(t-1)/x2 reads done

      // layer-0 epilogue: lane owns (pix = (mh*6+j)*16 + hi4*4 + r, ch0)
      const float bi0 = bx0[ch0], bf0 = bx0[32 + ch0];
      const float bg0 = bx0[64 + ch0], bo0 = bx0[96 + ch0];
#pragma unroll
      for (int j = 0; j < 6; ++j) {
        if (j < nt0) {
#pragma unroll
          for (int r = 0; r < 4; ++r) {
            int p = (mh * 6 + j) * 16 + hi4 * 4 + r;
            if (p < 168) {
              float c = c0r[j][r];
              float gi = a0[0][j][r] + bi0;
              float gf = a0[1][j][r] + bf0;
              float gc = a0[2][j][r] + bg0;
              float go = a0[3][j][r] + bo0;
              float wci = wc0[ch0 * 168 + p];
              float wcf = wc0[5376 + ch0 * 168 + p];
              float wco = wc0[10752 + ch0 * 168 + p];
              float ig = sigm(gi + c * wci);
              float fg = sigm(gf + c * wcf);
              float cn = fg * c + ig * ftanh(gc);
              float og = sigm(go + cn * wco);
              float hn = og * ftanh(cn);
              c0r[j][r] = cn;
              int iy = p / 24, ix = p - iy * 24;
              sh0[((iy + 1) * 26 + ix + 1) * 40 + ch0] = (__bf16)hn;
            }
          }
        }
      }
    }
    __syncthreads();     // h0(t) visible

    // ================= layer 1: 2 M-passes (all 4 waves) =================
    const float bi1 = bx1[ch1], bf1 = bx1[64 + ch1];
    const float bg1 = bx1[128 + ch1], bo1 = bx1[192 + ch1];

    // ---- pass 0: tiles 0..5 (pixels 0..95) ----
    {
      int b1h0[6], b1h1[6];
#pragma unroll
      for (int j = 0; j < 6; ++j) {
        int pr = j * 16 + lo16;
        int iy = pr / 24, ix = pr - iy * 24;
        b1h0[j] = (iy * 26 + ix) * 40;
        b1h1[j] = (iy * 26 + ix) * 72;
      }
      f32x4 a1[4][6];
#pragma unroll
      for (int g = 0; g < 4; ++g)
#pragma unroll
        for (int j = 0; j < 6; ++j) a1[g][j] = (f32x4){0.f, 0.f, 0.f, 0.f};

#pragma unroll 1
      for (int s = 0; s < 27; ++s) {
        bf16x8 bc[4];
#pragma unroll
        for (int g = 0; g < 4; ++g)
          bc[g] = *(const bf16x8*)(w1base + g * 55296 + s * 32);
        int toff;
        const __bf16* base;
        if (s < 9) {
          int ky = s / 3, kx = s - ky * 3;
          toff = (ky * 26 + kx) * 40 + hi4 * 8;
          base = sh0;
#pragma unroll
          for (int j = 0; j < 6; ++j) {
            bf16x8 af = *(const bf16x8*)(base + b1h0[j] + toff);
#pragma unroll
            for (int g = 0; g < 4; ++g)
              a1[g][j] = __builtin_amdgcn_mfma_f32_16x16x32_bf16(af, bc[g], a1[g][j], 0, 0, 0);
          }
        } else {
          int t2 = s - 9, tap = t2 >> 1, hf = t2 & 1;
          int ky = tap / 3, kx = tap - ky * 3;
          toff = (ky * 26 + kx) * 72 + hf * 32 + hi4 * 8;
          base = sh1;
#pragma unroll
          for (int j = 0; j < 6; ++j) {
            bf16x8 af = *(const bf16x8*)(base + b1h1[j] + toff);
#pragma unroll
            for (int g = 0; g < 4; ++g)
              a1[g][j] = __builtin_amdgcn_mfma_f32_16x16x32_bf16(af, bc[g], a1[g][j], 0, 0, 0);
          }
        }
      }
      // pass-0 epilogue: pixels 0..95 all real; h -> sstage (LDS), c in regs
#pragma unroll
      for (int j = 0; j < 6; ++j) {
#pragma unroll
        for (int r = 0; r < 4; ++r) {
          int p = j * 16 + hi4 * 4 + r;
          float c = c1rA[j][r];
          float gi = a1[0][j][r] + bi1;
          float gf = a1[1][j][r] + bf1;
          float gc = a1[2][j][r] + bg1;
          float go = a1[3][j][r] + bo1;
          float wci = wc1[ch1 * 168 + p];
          float wcf = wc1[10752 + ch1 * 168 + p];
          float wco = wc1[21504 + ch1 * 168 + p];
          float ig = sigm(gi + c * wci);
          float fg = sigm(gf + c * wcf);
          float cn = fg * c + ig * ftanh(gc);
          float og = sigm(go + cn * wco);
          c1rA[j][r] = cn;
          sstage[p * 64 + ch1] = (__bf16)(og * ftanh(cn));
        }
      }
    }

    // ---- pass 1: tiles 6..10 (pixels 96..167) ----
    {
      int b1h0[6], b1h1[6];
#pragma unroll
      for (int j = 0; j < 6; ++j) {
        int pr = (6 + j) * 16 + lo16;
        if (pr > 167) pr = 167;
        int iy = pr / 24, ix = pr - iy * 24;
        b1h0[j] = (iy * 26 + ix) * 40;
        b1h1[j] = (iy * 26 + ix) * 72;
      }
      f32x4 a1[4][6];
#pragma unroll
      for (int g = 0; g < 4; ++g)
#pragma unroll
        for (int j = 0; j < 6; ++j) a1[g][j] = (f32x4){0.f, 0.f, 0.f, 0.f};

#pragma unroll 1
      for (int s = 0; s < 27; ++s) {
        bf16x8 bc[4];
#pragma unroll
        for (int g = 0; g < 4; ++g)
          bc[g] = *(const bf16x8*)(w1base + g * 55296 + s * 32);
        if (s < 9) {
          int ky = s / 3, kx = s - ky * 3;
          int toff = (ky * 26 + kx) * 40 + hi4 * 8;
#pragma unroll
          for (int j = 0; j < 5; ++j) {   // tile 11 all-dummy: skip j=5
            bf16x8 af = *(const bf16x8*)(sh0 + b1h0[j] + toff);
#pragma unroll
            for (int g = 0; g < 4; ++g)
              a1[g][j] = __builtin_amdgcn_mfma_f32_16x16x32_bf16(af, bc[g], a1[g][j], 0, 0, 0);
          }
        } else {
          int t2 = s - 9, tap = t2 >> 1, hf = t2 & 1;
          int ky = tap / 3, kx = tap - ky * 3;
          int toff = (ky * 26 + kx) * 72 + hf * 32 + hi4 * 8;
#pragma unroll
          for (int j = 0; j < 5; ++j) {
            bf16x8 af = *(const bf16x8*)(sh1 + b1h1[j] + toff);
#pragma unroll
            for (int g = 0; g < 4; ++g)
              a1[g][j] = __builtin_amdgcn_mfma_f32_16x16x32_bf16(af, bc[g], a1[g][j], 0, 0, 0);
          }
        }
      }
      __syncthreads();   // all sh1(t-1)/sh0(t) reads done

      // commit pass-0 staged h(t): sstage[96][64] -> sh1 (halo layout)
      if (t < 192) {
        int p = t >> 1, half = (t & 1) * 32;
        int iy = p / 24, ix = p - iy * 24;
        __bf16* dst = sh1 + ((iy + 1) * 26 + ix + 1) * 72 + half;
        const __bf16* src = sstage + p * 64 + half;
#pragma unroll
        for (int q = 0; q < 4; ++q)
          *(bf16x8*)(dst + q * 8) = *(const bf16x8*)(src + q * 8);
      }

      // pass-1 epilogue: pixels 96..167 (mask), h -> sh1 directly
#pragma unroll
      for (int j = 0; j < 5; ++j) {
#pragma unroll
        for (int r = 0; r < 4; ++r) {
          int p = (6 + j) * 16 + hi4 * 4 + r;
          if (p < 168) {
            float c = c1rB[j][r];
            float gi = a1[0][j][r] + bi1;
            float gf = a1[1][j][r] + bf1;
            float gc = a1[2][j][r] + bg1;
            float go = a1[3][j][r] + bo1;
            float wci = wc1[ch1 * 168 + p];
            float wcf = wc1[10752 + ch1 * 168 + p];
            float wco = wc1[21504 + ch1 * 168 + p];
            float ig = sigm(gi + c * wci);
            float fg = sigm(gf + c * wcf);
            float cn = fg * c + ig * ftanh(gc);
            float og = sigm(go + cn * wco);
            float hn = og * ftanh(cn);
            c1rB[j][r] = cn;
            int iy = p / 24, ix = p - iy * 24;
            sh1[((iy + 1) * 26 + ix + 1) * 72 + ch1] = (__bf16)hn;
          }
        }
      }
    }
    __syncthreads();   // h1(t) visible
  }

  // ================= FC heads (h1 final in sh1) =================
  {
    const int o = t & 3, pg = t >> 2;    // o: 16 n's (o*16..); pg 0..63
    float part[16];
#pragma unroll
    for (int q = 0; q < 16; ++q) part[q] = 0.f;
#pragma unroll 1
    for (int jj = 0; jj < 3; ++jj) {
      int p = pg + 64 * jj;
      if (p < 168) {
        int iy = p / 24, ix = p - iy * 24;
        const __bf16* hrow = sh1 + ((iy + 1) * 26 + ix + 1) * 72;
        const __bf16* wrow = wfc2 + (size_t)p * 4096 + o * 16;
        for (int ch = 0; ch < 64; ++ch) {
          float hv = (float)hrow[ch];
          bf16x8 wv0 = *(const bf16x8*)(wrow + ch * 64);
          bf16x8 wv1 = *(const bf16x8*)(wrow + ch * 64 + 8);
#pragma unroll
          for (int q = 0; q < 8; ++q) {
            part[q] += hv * (float)wv0[q];
            part[8 + q] += hv * (float)wv1[q];
          }
        }
      }
    }
    float* sacc = (float*)sh0;   // reuse h0 area (16 KB needed, 18.7 KB avail)
    __syncthreads();             // h0 no longer needed
#pragma unroll
    for (int q = 0; q < 16; ++q) sacc[pg * 64 + o * 16 + q] = part[q];
    __syncthreads();
    if (t < 64) {
      float s = fc1b[t];
      for (int pg2 = 0; pg2 < 64; ++pg2) s += sacc[pg2 * 64 + t];
      out[(size_t)b * 128 + t] = fmaxf(s, 0.f);
    } else if (t < 128) {
      int j = t - 64;
      float s = exb[j];
      for (int k = 0; k < 24; ++k) s += x_ex[b * 24 + k] * exw[j * 24 + k];
      out[(size_t)b * 128 + 64 + j] = fmaxf(s, 0.f);
    }
  }
}

// ---------------- launcher ----------------
extern "C" void kernel_launch(void* const* d_in, const int* in_sizes, int n_in,
                              void* d_out, int out_size, void* d_ws, size_t ws_size,
                              hipStream_t stream) {
  const float* input = (const float*)d_in[0];
  const float* x_ex  = (const float*)d_in[1];
  const float* Wx0   = (const float*)d_in[2];
  const float* bx0   = (const float*)d_in[3];
  const float* Wh0   = (const float*)d_in[4];
  const float* Wc0   = (const float*)d_in[5];
  const float* Wx1   = (const float*)d_in[6];
  const float* bx1   = (const float*)d_in[7];
  const float* Wh1   = (const float*)d_in[8];
  const float* Wc1   = (const float*)d_in[9];
  const float* fc1w  = (const float*)d_in[10];
  const float* fc1b  = (const float*)d_in[11];
  const float* exw   = (const float*)d_in[12];
  const float* exb   = (const float*)d_in[13];
  (void)in_sizes; (void)n_in;

  if (ws_size < WS_NEED) {
    hipMemsetAsync(d_out, 0, (size_t)out_size * 4, stream);
    return;
  }

  char* ws = (char*)d_ws;
  __bf16* wp0  = (__bf16*)(ws + OFF_WP0);
  __bf16* wp1  = (__bf16*)(ws + OFF_WP1);
  __bf16* wfc2 = (__bf16*)(ws + OFF_WFC);

  pack_w0<<<160, 256, 0, stream>>>(Wx0, Wh0, wp0);
  pack_w1<<<864, 256, 0, stream>>>(Wx1, Wh1, wp1);
  pack_wfc<<<2688, 256, 0, stream>>>(fc1w, wfc2);

  convlstm_persistent<<<2048, 256, 0, stream>>>(
      input, x_ex, wp0, wp1, wfc2, bx0, bx1, Wc0, Wc1, fc1b, exw, exb,
      (float*)d_out);
}

// Round 8
// 3908.151 us; speedup vs baseline: 1.4277x; 1.4277x over previous
//
#include <hip/hip_runtime.h>
#include <math.h>

// ConvLSTM encoder, MI355X. Batch-persistent: one block per batch element,
// 256 threads (4 waves), 1 block/CU (LDS 140 KB). All state on-chip:
// h0/h1 bf16 ping-pong in LDS, c0 fp32 in LDS, c1 fp32 in registers.
// Convs = MFMA GEMMs (M=pixels, N=gates*ch, K=im2col taps from LDS).
// R7 lesson: 96-wide accumulators + 72 c-regs spilled even at VGPR=256.
// Here every accumulator block is [4][3]=48 regs (l0: 2 M-passes, l1: 4
// M-passes fully unrolled), c0 in LDS, ping-pong h (no staging/commit),
// 2 barriers/step, weight-fragment double-buffer. Demand ~180 << 256.

typedef __bf16 bf16x8 __attribute__((ext_vector_type(8)));
typedef float  f32x4  __attribute__((ext_vector_type(4)));

__device__ __forceinline__ float sigm(float x)  { return 1.f / (1.f + __expf(-x)); }
__device__ __forceinline__ float ftanh(float x) { float e = __expf(2.f * x); return 1.f - 2.f / (e + 1.f); }

// ---------------- workspace layout (bytes) ----------------
#define OFF_WP0  ((size_t)0)          // [128][320] bf16 = 81,920
#define OFF_WP1  ((size_t)81920)      // [256][864] bf16 = 442,368
#define OFF_WFC  ((size_t)524288)     // [168][64][64] bf16 = 1,376,256
#define WS_NEED  ((size_t)1900544)

#define SH0N 9360    // 9*26*40 bf16 per h0 buffer
#define SH1N 16848   // 9*26*72 bf16 per h1 buffer

// ---------------- weight pack kernels ----------------
// Wp0[n][k], n=gate*32+ch (128 rows), K=320: k<32 = im2col-x (ky*6+kx*2+cin,
// zero-padded 18->32); k>=32: (tap*32+c) from Wh0[n][c][tap].
__global__ void pack_w0(const float* __restrict__ wx0, const float* __restrict__ wh0,
                        __bf16* __restrict__ dst) {
  int o = blockIdx.x * 256 + threadIdx.x;
  if (o >= 128 * 320) return;
  int n = o / 320, k = o - n * 320;
  float v = 0.f;
  if (k < 32) {
    if (k < 18) {
      int ky = k / 6, rem = k - ky * 6, kx = rem >> 1, ci = rem & 1;
      v = wx0[(n * 2 + ci) * 9 + ky * 3 + kx];
    }
  } else {
    int tk = k - 32, tap = tk >> 5, c = tk & 31;
    v = wh0[(n * 32 + c) * 9 + tap];
  }
  dst[o] = (__bf16)v;
}

// Wp1[n][k], n=gate*64+ch (256 rows), K=864: k<288: tap*32+c from Wx1 (cin=32);
// k>=288: ((tap*2+half)*32+c) from Wh1[n][half*32+c][tap] (cin=64).
__global__ void pack_w1(const float* __restrict__ wx1, const float* __restrict__ wh1,
                        __bf16* __restrict__ dst) {
  int o = blockIdx.x * 256 + threadIdx.x;
  if (o >= 256 * 864) return;
  int n = o / 864, k = o - n * 864;
  float v;
  if (k < 288) {
    int tap = k >> 5, c = k & 31;
    v = wx1[(n * 32 + c) * 9 + tap];
  } else {
    int tk = k - 288, s2 = tk >> 5, c = tk & 31, tap = s2 >> 1, hf = s2 & 1;
    v = wh1[(n * 64 + hf * 32 + c) * 9 + tap];
  }
  dst[o] = (__bf16)v;
}

// Wfc2[pix][ch][n] bf16 = fc1_w[n][ch*168+pix]
__global__ void pack_wfc(const float* __restrict__ w, __bf16* __restrict__ dst) {
  int o = blockIdx.x * 256 + threadIdx.x;
  if (o >= 168 * 64 * 64) return;
  int pix = o >> 12, ch = (o >> 6) & 63, n = o & 63;
  dst[o] = (__bf16)w[n * 10752 + ch * 168 + pix];
}

// ---------------- the persistent ConvLSTM kernel ----------------
__global__ __launch_bounds__(256) void convlstm_persistent(
    const float* __restrict__ input, const float* __restrict__ x_ex,
    const __bf16* __restrict__ wp0, const __bf16* __restrict__ wp1,
    const __bf16* __restrict__ wfc2,
    const float* __restrict__ bx0, const float* __restrict__ bx1,
    const float* __restrict__ wc0, const float* __restrict__ wc1,
    const float* __restrict__ fc1b,
    const float* __restrict__ exw, const float* __restrict__ exb,
    float* __restrict__ out)
{
  __shared__ __bf16 sh0[2 * SH0N];   // h0 ping-pong, [y][x][40] halo (37,440 B)
  __shared__ __bf16 sh1[2 * SH1N];   // h1 ping-pong, [y][x][72] halo (67,392 B)
  __shared__ __bf16 sx2[168 * 40];   // im2col x [pix][40], k<18 used (13,440 B)
  __shared__ float  c0l[168 * 33];   // c0 state fp32, [pix][33]      (22,176 B)
  // total 140,448 B -> 1 block/CU; 4 waves -> allocator grants 256 VGPR.

  const int b = blockIdx.x;
  const int t = threadIdx.x;
  const int w = t >> 6, L = t & 63;
  const int lo16 = L & 15, hi4 = L >> 4;

  // ---- zero LDS ----
  {
    int* p0 = (int*)sh0;
    for (int i = t; i < SH0N; i += 256) p0[i] = 0;          // 2*SH0N bf16
    int* p1 = (int*)sh1;
    for (int i = t; i < SH1N; i += 256) p1[i] = 0;          // 2*SH1N bf16
    int* p2 = (int*)sx2;
    for (int i = t; i < 168 * 40 / 2; i += 256) p2[i] = 0;
    for (int i = t; i < 168 * 33; i += 256) c0l[i] = 0.f;
  }
  __syncthreads();

  // ---- build im2col x2 (time-constant), [pix][40], k = ky*6+kx*2+cin ----
  if (t < 168) {
    int iy = t / 24, ix = t - iy * 24;
    __bf16* dst = sx2 + t * 40;
    for (int ky = 0; ky < 3; ++ky) {
      int y = iy + ky - 1;
      if (y < 0 || y >= 7) continue;
      for (int kx = 0; kx < 3; ++kx) {
        int x = ix + kx - 1;
        if (x < 0 || x >= 24) continue;
        int k0 = ky * 6 + kx * 2;
        dst[k0 + 0] = (__bf16)input[((b * 2 + 0) * 7 + y) * 24 + x];
        dst[k0 + 1] = (__bf16)input[((b * 2 + 1) * 7 + y) * 24 + x];
      }
    }
  }

  // ---- per-wave / per-lane constants ----
  // layer 0: wave = (mh 0..1) x (chh 0..1); pass q: tiles mh*6+q*3+j, 16 ch
  // layer 1: wave = chq (0..3) -> 16 ch; pass p: tiles p*3+j
  const int mh = w >> 1, chh = w & 1;
  const int ch0 = chh * 16 + lo16;     // layer-0 channel (0..31)
  const int ch1 = w * 16 + lo16;       // layer-1 channel (0..63)

  const __bf16* w0base = wp0 + (size_t)ch0 * 320 + hi4 * 8;   // + g*10240
  const __bf16* w1base = wp1 + (size_t)ch1 * 864 + hi4 * 8;   // + g*55296

  const float bi0 = bx0[ch0], bf0 = bx0[32 + ch0];
  const float bg0 = bx0[64 + ch0], bo0 = bx0[96 + ch0];
  const float bi1 = bx1[ch1], bf1 = bx1[64 + ch1];
  const float bg1 = bx1[128 + ch1], bo1 = bx1[192 + ch1];

  float c1r[4][3][4];
#pragma unroll
  for (int p = 0; p < 4; ++p)
#pragma unroll
    for (int j = 0; j < 3; ++j)
#pragma unroll
      for (int r = 0; r < 4; ++r) c1r[p][j][r] = 0.f;

  __syncthreads();   // x2 + zeroed state visible

#pragma unroll 1
  for (int st = 0; st < 7; ++st) {
    const __bf16* h0r = sh0 + (st & 1) * SH0N;
    __bf16*       h0w = sh0 + ((st + 1) & 1) * SH0N;
    const __bf16* h1r = sh1 + (st & 1) * SH1N;
    __bf16*       h1w = sh1 + ((st + 1) & 1) * SH1N;

    // ================= layer 0: 2 M-passes =================
#pragma unroll 1
    for (int q = 0; q < 2; ++q) {
      const int tb = mh * 6 + q * 3;               // first tile of this pass
      const int ntq = (mh == 1 && q == 1) ? 2 : 3; // tile 11 all-dummy
      int b0h[3], b0x[3];
#pragma unroll
      for (int j = 0; j < 3; ++j) {
        int pr = (tb + j) * 16 + lo16;
        if (pr > 167) pr = 167;
        int iy = pr / 24, ix = pr - iy * 24;
        b0h[j] = (iy * 26 + ix) * 40;
        b0x[j] = pr * 40 + hi4 * 8;
      }
      f32x4 a0[4][3];
#pragma unroll
      for (int g = 0; g < 4; ++g)
#pragma unroll
        for (int j = 0; j < 3; ++j) a0[g][j] = (f32x4){0.f, 0.f, 0.f, 0.f};

      bf16x8 bc[4], bn[4];
#pragma unroll
      for (int g = 0; g < 4; ++g) bc[g] = *(const bf16x8*)(w0base + g * 10240);

#pragma unroll 1
      for (int s = 0; s < 10; ++s) {
        int sp = (s < 9) ? s + 1 : 9;
#pragma unroll
        for (int g = 0; g < 4; ++g)
          bn[g] = *(const bf16x8*)(w0base + g * 10240 + sp * 32);
        if (s == 0) {
#pragma unroll
          for (int j = 0; j < 3; ++j) {
            if (j < ntq) {
              bf16x8 af = *(const bf16x8*)(sx2 + b0x[j]);
#pragma unroll
              for (int g = 0; g < 4; ++g)
                a0[g][j] = __builtin_amdgcn_mfma_f32_16x16x32_bf16(af, bc[g], a0[g][j], 0, 0, 0);
            }
          }
        } else {
          int tap = s - 1, ky = tap / 3, kx = tap - ky * 3;
          int toff = (ky * 26 + kx) * 40 + hi4 * 8;
#pragma unroll
          for (int j = 0; j < 3; ++j) {
            if (j < ntq) {
              bf16x8 af = *(const bf16x8*)(h0r + b0h[j] + toff);
#pragma unroll
              for (int g = 0; g < 4; ++g)
                a0[g][j] = __builtin_amdgcn_mfma_f32_16x16x32_bf16(af, bc[g], a0[g][j], 0, 0, 0);
            }
          }
        }
#pragma unroll
        for (int g = 0; g < 4; ++g) bc[g] = bn[g];
      }

      // epilogue: lane owns (pix = (tb+j)*16 + hi4*4 + r, ch0); c0 in LDS
#pragma unroll
      for (int j = 0; j < 3; ++j) {
        if (j < ntq) {
#pragma unroll
          for (int r = 0; r < 4; ++r) {
            int p = (tb + j) * 16 + hi4 * 4 + r;
            if (p < 168) {
              float c = c0l[p * 33 + ch0];
              float gi = a0[0][j][r] + bi0;
              float gf = a0[1][j][r] + bf0;
              float gc = a0[2][j][r] + bg0;
              float go = a0[3][j][r] + bo0;
              float wci = wc0[ch0 * 168 + p];
              float wcf = wc0[5376 + ch0 * 168 + p];
              float wco = wc0[10752 + ch0 * 168 + p];
              float ig = sigm(gi + c * wci);
              float fg = sigm(gf + c * wcf);
              float cn = fg * c + ig * ftanh(gc);
              float og = sigm(go + cn * wco);
              float hn = og * ftanh(cn);
              c0l[p * 33 + ch0] = cn;
              int iy = p / 24, ix = p - iy * 24;
              h0w[((iy + 1) * 26 + ix + 1) * 40 + ch0] = (__bf16)hn;
            }
          }
        }
      }
    }
    __syncthreads();   // h0(t) visible (and all h0(t-1)/x2 reads done)

    // ================= layer 1: 4 M-passes (fully unrolled) =================
#pragma unroll
    for (int p4 = 0; p4 < 4; ++p4) {
      const int ntp = (p4 == 3) ? 2 : 3;           // tile 11 all-dummy
      int b1h0[3], b1h1[3];
#pragma unroll
      for (int j = 0; j < 3; ++j) {
        int pr = (p4 * 3 + j) * 16 + lo16;
        if (pr > 167) pr = 167;
        int iy = pr / 24, ix = pr - iy * 24;
        b1h0[j] = (iy * 26 + ix) * 40;
        b1h1[j] = (iy * 26 + ix) * 72;
      }
      f32x4 a1[4][3];
#pragma unroll
      for (int g = 0; g < 4; ++g)
#pragma unroll
        for (int j = 0; j < 3; ++j) a1[g][j] = (f32x4){0.f, 0.f, 0.f, 0.f};

      bf16x8 bc[4], bn[4];
#pragma unroll
      for (int g = 0; g < 4; ++g) bc[g] = *(const bf16x8*)(w1base + g * 55296);

#pragma unroll 1
      for (int s = 0; s < 27; ++s) {
        int sp = (s < 26) ? s + 1 : 26;
#pragma unroll
        for (int g = 0; g < 4; ++g)
          bn[g] = *(const bf16x8*)(w1base + g * 55296 + sp * 32);
        if (s < 9) {
          int ky = s / 3, kx = s - ky * 3;
          int toff = (ky * 26 + kx) * 40 + hi4 * 8;
#pragma unroll
          for (int j = 0; j < 3; ++j) {
            if (j < ntp) {
              bf16x8 af = *(const bf16x8*)(h0w + b1h0[j] + toff);  // h0(t)
#pragma unroll
              for (int g = 0; g < 4; ++g)
                a1[g][j] = __builtin_amdgcn_mfma_f32_16x16x32_bf16(af, bc[g], a1[g][j], 0, 0, 0);
            }
          }
        } else {
          int t2 = s - 9, tap = t2 >> 1, hf = t2 & 1;
          int ky = tap / 3, kx = tap - ky * 3;
          int toff = (ky * 26 + kx) * 72 + hf * 32 + hi4 * 8;
#pragma unroll
          for (int j = 0; j < 3; ++j) {
            if (j < ntp) {
              bf16x8 af = *(const bf16x8*)(h1r + b1h1[j] + toff);  // h1(t-1)
#pragma unroll
              for (int g = 0; g < 4; ++g)
                a1[g][j] = __builtin_amdgcn_mfma_f32_16x16x32_bf16(af, bc[g], a1[g][j], 0, 0, 0);
            }
          }
        }
#pragma unroll
        for (int g = 0; g < 4; ++g) bc[g] = bn[g];
      }

      // epilogue: lane owns (pix = (p4*3+j)*16 + hi4*4 + r, ch1); h -> h1w
#pragma unroll
      for (int j = 0; j < 3; ++j) {
        if (j < ntp) {
#pragma unroll
          for (int r = 0; r < 4; ++r) {
            int p = (p4 * 3 + j) * 16 + hi4 * 4 + r;
            if (p < 168) {
              float c = c1r[p4][j][r];
              float gi = a1[0][j][r] + bi1;
              float gf = a1[1][j][r] + bf1;
              float gc = a1[2][j][r] + bg1;
              float go = a1[3][j][r] + bo1;
              float wci = wc1[ch1 * 168 + p];
              float wcf = wc1[10752 + ch1 * 168 + p];
              float wco = wc1[21504 + ch1 * 168 + p];
              float ig = sigm(gi + c * wci);
              float fg = sigm(gf + c * wcf);
              float cn = fg * c + ig * ftanh(gc);
              float og = sigm(go + cn * wco);
              float hn = og * ftanh(cn);
              c1r[p4][j][r] = cn;
              int iy = p / 24, ix = p - iy * 24;
              h1w[((iy + 1) * 26 + ix + 1) * 72 + ch1] = (__bf16)hn;
            }
          }
        }
      }
    }
    __syncthreads();   // h1(t) visible (and all h1(t-1)/h0(t) reads done)
  }

  // ================= FC heads (h1 final in sh1 buffer 1) =================
  {
    const __bf16* h1f = sh1 + SH1N;      // (st=6 wrote buffer (6+1)&1 = 1)
    const int o = t & 3, pg = t >> 2;    // o: 16 n's (o*16..); pg 0..63
    float part[16];
#pragma unroll
    for (int q = 0; q < 16; ++q) part[q] = 0.f;
#pragma unroll 1
    for (int jj = 0; jj < 3; ++jj) {
      int p = pg + 64 * jj;
      if (p < 168) {
        int iy = p / 24, ix = p - iy * 24;
        const __bf16* hrow = h1f + ((iy + 1) * 26 + ix + 1) * 72;
        const __bf16* wrow = wfc2 + (size_t)p * 4096 + o * 16;
        for (int ch = 0; ch < 64; ++ch) {
          float hv = (float)hrow[ch];
          bf16x8 wv0 = *(const bf16x8*)(wrow + ch * 64);
          bf16x8 wv1 = *(const bf16x8*)(wrow + ch * 64 + 8);
#pragma unroll
          for (int q = 0; q < 8; ++q) {
            part[q] += hv * (float)wv0[q];
            part[8 + q] += hv * (float)wv1[q];
          }
        }
      }
    }
    float* sacc = c0l;   // c0 state dead after last step; 16 KB needed
    __syncthreads();
#pragma unroll
    for (int q = 0; q < 16; ++q) sacc[pg * 64 + o * 16 + q] = part[q];
    __syncthreads();
    if (t < 64) {
      float s = fc1b[t];
      for (int pg2 = 0; pg2 < 64; ++pg2) s += sacc[pg2 * 64 + t];
      out[(size_t)b * 128 + t] = fmaxf(s, 0.f);
    } else if (t < 128) {
      int j = t - 64;
      float s = exb[j];
      for (int k = 0; k < 24; ++k) s += x_ex[b * 24 + k] * exw[j * 24 + k];
      out[(size_t)b * 128 + 64 + j] = fmaxf(s, 0.f);
    }
  }
}

// ---------------- launcher ----------------
extern "C" void kernel_launch(void* const* d_in, const int* in_sizes, int n_in,
                              void* d_out, int out_size, void* d_ws, size_t ws_size,
                              hipStream_t stream) {
  const float* input = (const float*)d_in[0];
  const float* x_ex  = (const float*)d_in[1];
  const float* Wx0   = (const float*)d_in[2];
  const float* bx0   = (const float*)d_in[3];
  const float* Wh0   = (const float*)d_in[4];
  const float* Wc0   = (const float*)d_in[5];
  const float* Wx1   = (const float*)d_in[6];
  const float* bx1   = (const float*)d_in[7];
  const float* Wh1   = (const float*)d_in[8];
  const float* Wc1   = (const float*)d_in[9];
  const float* fc1w  = (const float*)d_in[10];
  const float* fc1b  = (const float*)d_in[11];
  const float* exw   = (const float*)d_in[12];
  const float* exb   = (const float*)d_in[13];
  (void)in_sizes; (void)n_in;

  if (ws_size < WS_NEED) {
    hipMemsetAsync(d_out, 0, (size_t)out_size * 4, stream);
    return;
  }

  char* ws = (char*)d_ws;
  __bf16* wp0  = (__bf16*)(ws + OFF_WP0);
  __bf16* wp1  = (__bf16*)(ws + OFF_WP1);
  __bf16* wfc2 = (__bf16*)(ws + OFF_WFC);

  pack_w0<<<160, 256, 0, stream>>>(Wx0, Wh0, wp0);
  pack_w1<<<864, 256, 0, stream>>>(Wx1, Wh1, wp1);
  pack_wfc<<<2688, 256, 0, stream>>>(fc1w, wfc2);

  convlstm_persistent<<<2048, 256, 0, stream>>>(
      input, x_ex, wp0, wp1, wfc2, bx0, bx1, Wc0, Wc1, fc1b, exw, exb,
      (float*)d_out);
}

// Round 9
// 2879.235 us; speedup vs baseline: 1.9379x; 1.3574x over previous
//
#include <hip/hip_runtime.h>
#include <math.h>

// ConvLSTM encoder, MI355X. Batch-persistent: one block per batch element,
// 256 threads (4 waves), 1 block/CU (LDS 140 KB). All state on-chip:
// h0/h1 bf16 ping-pong in LDS, c0 fp32 in LDS, c1 fp32 in registers.
// Convs = MFMA GEMMs (M=pixels, N=gates*ch, K=im2col taps from LDS).
// R8 was spill-free but latency-bound (1 wave/SIMD, MfmaUtil 13.5%):
// weight loads were 16-way scattered and ds_read->MFMA serialized. R9:
// (a) fragment-ordered weight packs -> every weight load is 64x16B
// contiguous; (b) software-pipelined K-loops (prefetch s+1 A-frags +
// B-frags before s's MFMAs).

typedef __bf16 bf16x8 __attribute__((ext_vector_type(8)));
typedef float  f32x4  __attribute__((ext_vector_type(4)));

__device__ __forceinline__ float sigm(float x)  { return 1.f / (1.f + __expf(-x)); }
__device__ __forceinline__ float ftanh(float x) { float e = __expf(2.f * x); return 1.f - 2.f / (e + 1.f); }

// ---------------- workspace layout (bytes) ----------------
#define OFF_WP0  ((size_t)0)          // [2][10][4][64][8] bf16 = 81,920
#define OFF_WP1  ((size_t)81920)      // [4][27][4][64][8] bf16 = 442,368
#define OFF_WFC  ((size_t)524288)     // [168][64][64] bf16 = 1,376,256
#define WS_NEED  ((size_t)1900544)

#define SH0N 9360    // 9*26*40 bf16 per h0 buffer
#define SH1N 16848   // 9*26*72 bf16 per h1 buffer

// ---------------- weight pack kernels (fragment-ordered) ----------------
// wp0f[((chh*10+s)*4+g)*512 + L*8 + e] = W0(n = g*32+chh*16+(L&15),
//   k = s*32+(L>>4)*8+e), K-order: k<32 im2col-x (k<18 real), k>=32 h-taps.
__global__ void pack_w0(const float* __restrict__ wx0, const float* __restrict__ wh0,
                        __bf16* __restrict__ dst) {
  int o = blockIdx.x * 256 + threadIdx.x;
  if (o >= 40960) return;
  int e = o & 7, L = (o >> 3) & 63;
  int idx = o >> 9;
  int g = idx & 3, sidx = idx >> 2;
  int s = sidx % 10, chh = sidx / 10;
  int n = g * 32 + chh * 16 + (L & 15);
  int k = s * 32 + (L >> 4) * 8 + e;
  float v = 0.f;
  if (k < 32) {
    if (k < 18) {
      int ky = k / 6, rem = k - ky * 6, kx = rem >> 1, ci = rem & 1;
      v = wx0[(n * 2 + ci) * 9 + ky * 3 + kx];
    }
  } else {
    int tk = k - 32, tap = tk >> 5, c = tk & 31;
    v = wh0[(n * 32 + c) * 9 + tap];
  }
  dst[o] = (__bf16)v;
}

// wp1f[((chq*27+s)*4+g)*512 + L*8 + e] = W1(n = g*64+chq*16+(L&15),
//   k = s*32+(L>>4)*8+e), K-order: k<288 x-conv taps, k>=288 h-taps.
__global__ void pack_w1(const float* __restrict__ wx1, const float* __restrict__ wh1,
                        __bf16* __restrict__ dst) {
  int o = blockIdx.x * 256 + threadIdx.x;
  if (o >= 221184) return;
  int e = o & 7, L = (o >> 3) & 63;
  int idx = o >> 9;
  int g = idx & 3, sidx = idx >> 2;
  int s = sidx % 27, chq = sidx / 27;
  int n = g * 64 + chq * 16 + (L & 15);
  int k = s * 32 + (L >> 4) * 8 + e;
  float v;
  if (k < 288) {
    int tap = k >> 5, c = k & 31;
    v = wx1[(n * 32 + c) * 9 + tap];
  } else {
    int tk = k - 288, s2 = tk >> 5, c = tk & 31, tap = s2 >> 1, hf = s2 & 1;
    v = wh1[(n * 64 + hf * 32 + c) * 9 + tap];
  }
  dst[o] = (__bf16)v;
}

// Wfc2[pix][ch][n] bf16 = fc1_w[n][ch*168+pix]
__global__ void pack_wfc(const float* __restrict__ w, __bf16* __restrict__ dst) {
  int o = blockIdx.x * 256 + threadIdx.x;
  if (o >= 168 * 64 * 64) return;
  int pix = o >> 12, ch = (o >> 6) & 63, n = o & 63;
  dst[o] = (__bf16)w[n * 10752 + ch * 168 + pix];
}

// ---------------- the persistent ConvLSTM kernel ----------------
__global__ __launch_bounds__(256) void convlstm_persistent(
    const float* __restrict__ input, const float* __restrict__ x_ex,
    const __bf16* __restrict__ wp0, const __bf16* __restrict__ wp1,
    const __bf16* __restrict__ wfc2,
    const float* __restrict__ bx0, const float* __restrict__ bx1,
    const float* __restrict__ wc0, const float* __restrict__ wc1,
    const float* __restrict__ fc1b,
    const float* __restrict__ exw, const float* __restrict__ exb,
    float* __restrict__ out)
{
  __shared__ __bf16 sh0[2 * SH0N];   // h0 ping-pong, [y][x][40] halo (37,440 B)
  __shared__ __bf16 sh1[2 * SH1N];   // h1 ping-pong, [y][x][72] halo (67,392 B)
  __shared__ __bf16 sx2[168 * 40];   // im2col x [pix][40], k<18 used (13,440 B)
  __shared__ float  c0l[168 * 33];   // c0 state fp32, [pix][33]      (22,176 B)

  const int b = blockIdx.x;
  const int t = threadIdx.x;
  const int w = t >> 6, L = t & 63;
  const int lo16 = L & 15, hi4 = L >> 4;

  // ---- zero LDS ----
  {
    int* p0 = (int*)sh0;
    for (int i = t; i < SH0N; i += 256) p0[i] = 0;
    int* p1 = (int*)sh1;
    for (int i = t; i < SH1N; i += 256) p1[i] = 0;
    int* p2 = (int*)sx2;
    for (int i = t; i < 168 * 40 / 2; i += 256) p2[i] = 0;
    for (int i = t; i < 168 * 33; i += 256) c0l[i] = 0.f;
  }
  __syncthreads();

  // ---- build im2col x2 (time-constant), [pix][40], k = ky*6+kx*2+cin ----
  if (t < 168) {
    int iy = t / 24, ix = t - iy * 24;
    __bf16* dst = sx2 + t * 40;
    for (int ky = 0; ky < 3; ++ky) {
      int y = iy + ky - 1;
      if (y < 0 || y >= 7) continue;
      for (int kx = 0; kx < 3; ++kx) {
        int x = ix + kx - 1;
        if (x < 0 || x >= 24) continue;
        int k0 = ky * 6 + kx * 2;
        dst[k0 + 0] = (__bf16)input[((b * 2 + 0) * 7 + y) * 24 + x];
        dst[k0 + 1] = (__bf16)input[((b * 2 + 1) * 7 + y) * 24 + x];
      }
    }
  }

  // ---- per-wave / per-lane constants ----
  const int mh = w >> 1, chh = w & 1;
  const int ch0 = chh * 16 + lo16;     // layer-0 channel (0..31)
  const int ch1 = w * 16 + lo16;       // layer-1 channel (0..63)

  const __bf16* w0f = wp0 + chh * 20480 + L * 8;   // + (s*4+g)*512
  const __bf16* w1f = wp1 + w * 55296 + L * 8;     // + (s*4+g)*512

  const float bi0 = bx0[ch0], bf0 = bx0[32 + ch0];
  const float bg0 = bx0[64 + ch0], bo0 = bx0[96 + ch0];
  const float bi1 = bx1[ch1], bf1 = bx1[64 + ch1];
  const float bg1 = bx1[128 + ch1], bo1 = bx1[192 + ch1];

  float c1r[4][3][4];
#pragma unroll
  for (int p = 0; p < 4; ++p)
#pragma unroll
    for (int j = 0; j < 3; ++j)
#pragma unroll
      for (int r = 0; r < 4; ++r) c1r[p][j][r] = 0.f;

  __syncthreads();   // x2 + zeroed state visible

#pragma unroll 1
  for (int st = 0; st < 7; ++st) {
    const __bf16* h0r = sh0 + (st & 1) * SH0N;
    __bf16*       h0w = sh0 + ((st + 1) & 1) * SH0N;
    const __bf16* h1r = sh1 + (st & 1) * SH1N;
    __bf16*       h1w = sh1 + ((st + 1) & 1) * SH1N;

    // ================= layer 0: 2 M-passes =================
#pragma unroll 1
    for (int q = 0; q < 2; ++q) {
      const int tb = mh * 6 + q * 3;               // first tile of this pass
      const int ntq = (mh == 1 && q == 1) ? 2 : 3; // tile 11 all-dummy
      int b0h[3], b0x[3];
#pragma unroll
      for (int j = 0; j < 3; ++j) {
        int pr = (tb + j) * 16 + lo16;
        if (pr > 167) pr = 167;
        int iy = pr / 24, ix = pr - iy * 24;
        b0h[j] = (iy * 26 + ix) * 40;
        b0x[j] = pr * 40 + hi4 * 8;
      }
      f32x4 a0[4][3];
#pragma unroll
      for (int g = 0; g < 4; ++g)
#pragma unroll
        for (int j = 0; j < 3; ++j) a0[g][j] = (f32x4){0.f, 0.f, 0.f, 0.f};

      // prologue: s=0 fragments
      bf16x8 afc[3], bcc[4];
#pragma unroll
      for (int j = 0; j < 3; ++j) afc[j] = *(const bf16x8*)(sx2 + b0x[j]);
#pragma unroll
      for (int g = 0; g < 4; ++g) bcc[g] = *(const bf16x8*)(w0f + g * 512);

#pragma unroll 1
      for (int s = 0; s < 10; ++s) {
        int sp = (s < 9) ? s + 1 : 9;
        // prefetch s+1 (weights coalesced; A-frags from h0(t-1) taps)
        bf16x8 afn[3], bcn[4];
#pragma unroll
        for (int g = 0; g < 4; ++g)
          bcn[g] = *(const bf16x8*)(w0f + (sp * 4 + g) * 512);
        {
          int tap = sp - 1, ky = tap / 3, kx = tap - ky * 3;
          int toff = (ky * 26 + kx) * 40 + hi4 * 8;
#pragma unroll
          for (int j = 0; j < 3; ++j)
            afn[j] = *(const bf16x8*)(h0r + b0h[j] + toff);
        }
        // compute s (all 3 tiles; dummy masked in epilogue)
#pragma unroll
        for (int j = 0; j < 3; ++j)
#pragma unroll
          for (int g = 0; g < 4; ++g)
            a0[g][j] = __builtin_amdgcn_mfma_f32_16x16x32_bf16(afc[j], bcc[g], a0[g][j], 0, 0, 0);
#pragma unroll
        for (int j = 0; j < 3; ++j) afc[j] = afn[j];
#pragma unroll
        for (int g = 0; g < 4; ++g) bcc[g] = bcn[g];
      }

      // epilogue: lane owns (pix = (tb+j)*16 + hi4*4 + r, ch0); c0 in LDS
#pragma unroll
      for (int j = 0; j < 3; ++j) {
        if (j < ntq) {
#pragma unroll
          for (int r = 0; r < 4; ++r) {
            int p = (tb + j) * 16 + hi4 * 4 + r;
            if (p < 168) {
              float c = c0l[p * 33 + ch0];
              float gi = a0[0][j][r] + bi0;
              float gf = a0[1][j][r] + bf0;
              float gc = a0[2][j][r] + bg0;
              float go = a0[3][j][r] + bo0;
              float wci = wc0[ch0 * 168 + p];
              float wcf = wc0[5376 + ch0 * 168 + p];
              float wco = wc0[10752 + ch0 * 168 + p];
              float ig = sigm(gi + c * wci);
              float fg = sigm(gf + c * wcf);
              float cn = fg * c + ig * ftanh(gc);
              float og = sigm(go + cn * wco);
              float hn = og * ftanh(cn);
              c0l[p * 33 + ch0] = cn;
              int iy = p / 24, ix = p - iy * 24;
              h0w[((iy + 1) * 26 + ix + 1) * 40 + ch0] = (__bf16)hn;
            }
          }
        }
      }
    }
    __syncthreads();   // h0(t) visible (and all h0(t-1)/x2 reads done)

    // ================= layer 1: 4 M-passes (fully unrolled) =================
#pragma unroll
    for (int p4 = 0; p4 < 4; ++p4) {
      const int ntp = (p4 == 3) ? 2 : 3;           // tile 11 all-dummy
      int b1h0[3], b1h1[3];
#pragma unroll
      for (int j = 0; j < 3; ++j) {
        int pr = (p4 * 3 + j) * 16 + lo16;
        if (pr > 167) pr = 167;
        int iy = pr / 24, ix = pr - iy * 24;
        b1h0[j] = (iy * 26 + ix) * 40;
        b1h1[j] = (iy * 26 + ix) * 72;
      }
      f32x4 a1[4][3];
#pragma unroll
      for (int g = 0; g < 4; ++g)
#pragma unroll
        for (int j = 0; j < 3; ++j) a1[g][j] = (f32x4){0.f, 0.f, 0.f, 0.f};

      // prologue: s=0 (h0(t), tap 0 -> toff = hi4*8)
      bf16x8 afc[3], bcc[4];
#pragma unroll
      for (int j = 0; j < 3; ++j)
        afc[j] = *(const bf16x8*)(h0w + b1h0[j] + hi4 * 8);
#pragma unroll
      for (int g = 0; g < 4; ++g) bcc[g] = *(const bf16x8*)(w1f + g * 512);

#pragma unroll 1
      for (int s = 0; s < 27; ++s) {
        int sp = (s < 26) ? s + 1 : 26;
        bf16x8 afn[3], bcn[4];
#pragma unroll
        for (int g = 0; g < 4; ++g)
          bcn[g] = *(const bf16x8*)(w1f + (sp * 4 + g) * 512);
        if (sp < 9) {
          int ky = sp / 3, kx = sp - ky * 3;
          int toff = (ky * 26 + kx) * 40 + hi4 * 8;
#pragma unroll
          for (int j = 0; j < 3; ++j)
            afn[j] = *(const bf16x8*)(h0w + b1h0[j] + toff);
        } else {
          int t2 = sp - 9, tap = t2 >> 1, hf = t2 & 1;
          int ky = tap / 3, kx = tap - ky * 3;
          int toff = (ky * 26 + kx) * 72 + hf * 32 + hi4 * 8;
#pragma unroll
          for (int j = 0; j < 3; ++j)
            afn[j] = *(const bf16x8*)(h1r + b1h1[j] + toff);
        }
#pragma unroll
        for (int j = 0; j < 3; ++j) {
          if (j < ntp) {
#pragma unroll
            for (int g = 0; g < 4; ++g)
              a1[g][j] = __builtin_amdgcn_mfma_f32_16x16x32_bf16(afc[j], bcc[g], a1[g][j], 0, 0, 0);
          }
        }
#pragma unroll
        for (int j = 0; j < 3; ++j) afc[j] = afn[j];
#pragma unroll
        for (int g = 0; g < 4; ++g) bcc[g] = bcn[g];
      }

      // epilogue: lane owns (pix = (p4*3+j)*16 + hi4*4 + r, ch1); h -> h1w
#pragma unroll
      for (int j = 0; j < 3; ++j) {
        if (j < ntp) {
#pragma unroll
          for (int r = 0; r < 4; ++r) {
            int p = (p4 * 3 + j) * 16 + hi4 * 4 + r;
            if (p < 168) {
              float c = c1r[p4][j][r];
              float gi = a1[0][j][r] + bi1;
              float gf = a1[1][j][r] + bf1;
              float gc = a1[2][j][r] + bg1;
              float go = a1[3][j][r] + bo1;
              float wci = wc1[ch1 * 168 + p];
              float wcf = wc1[10752 + ch1 * 168 + p];
              float wco = wc1[21504 + ch1 * 168 + p];
              float ig = sigm(gi + c * wci);
              float fg = sigm(gf + c * wcf);
              float cn = fg * c + ig * ftanh(gc);
              float og = sigm(go + cn * wco);
              float hn = og * ftanh(cn);
              c1r[p4][j][r] = cn;
              int iy = p / 24, ix = p - iy * 24;
              h1w[((iy + 1) * 26 + ix + 1) * 72 + ch1] = (__bf16)hn;
            }
          }
        }
      }
    }
    __syncthreads();   // h1(t) visible (and all h1(t-1)/h0(t) reads done)
  }

  // ================= FC heads (h1 final in sh1 buffer 1) =================
  {
    const __bf16* h1f = sh1 + SH1N;      // (st=6 wrote buffer (6+1)&1 = 1)
    const int o = t & 3, pg = t >> 2;    // o: 16 n's (o*16..); pg 0..63
    float part[16];
#pragma unroll
    for (int q = 0; q < 16; ++q) part[q] = 0.f;
#pragma unroll 1
    for (int jj = 0; jj < 3; ++jj) {
      int p = pg + 64 * jj;
      if (p < 168) {
        int iy = p / 24, ix = p - iy * 24;
        const __bf16* hrow = h1f + ((iy + 1) * 26 + ix + 1) * 72;
        const __bf16* wrow = wfc2 + (size_t)p * 4096 + o * 16;
        for (int ch = 0; ch < 64; ++ch) {
          float hv = (float)hrow[ch];
          bf16x8 wv0 = *(const bf16x8*)(wrow + ch * 64);
          bf16x8 wv1 = *(const bf16x8*)(wrow + ch * 64 + 8);
#pragma unroll
          for (int q = 0; q < 8; ++q) {
            part[q] += hv * (float)wv0[q];
            part[8 + q] += hv * (float)wv1[q];
          }
        }
      }
    }
    float* sacc = c0l;   // c0 state dead after last step; 16 KB needed
    __syncthreads();
#pragma unroll
    for (int q = 0; q < 16; ++q) sacc[pg * 64 + o * 16 + q] = part[q];
    __syncthreads();
    if (t < 64) {
      float s = fc1b[t];
      for (int pg2 = 0; pg2 < 64; ++pg2) s += sacc[pg2 * 64 + t];
      out[(size_t)b * 128 + t] = fmaxf(s, 0.f);
    } else if (t < 128) {
      int j = t - 64;
      float s = exb[j];
      for (int k = 0; k < 24; ++k) s += x_ex[b * 24 + k] * exw[j * 24 + k];
      out[(size_t)b * 128 + 64 + j] = fmaxf(s, 0.f);
    }
  }
}

// ---------------- launcher ----------------
extern "C" void kernel_launch(void* const* d_in, const int* in_sizes, int n_in,
                              void* d_out, int out_size, void* d_ws, size_t ws_size,
                              hipStream_t stream) {
  const float* input = (const float*)d_in[0];
  const float* x_ex  = (const float*)d_in[1];
  const float* Wx0   = (const float*)d_in[2];
  const float* bx0   = (const float*)d_in[3];
  const float* Wh0   = (const float*)d_in[4];
  const float* Wc0   = (const float*)d_in[5];
  const float* Wx1   = (const float*)d_in[6];
  const float* bx1   = (const float*)d_in[7];
  const float* Wh1   = (const float*)d_in[8];
  const float* Wc1   = (const float*)d_in[9];
  const float* fc1w  = (const float*)d_in[10];
  const float* fc1b  = (const float*)d_in[11];
  const float* exw   = (const float*)d_in[12];
  const float* exb   = (const float*)d_in[13];
  (void)in_sizes; (void)n_in;

  if (ws_size < WS_NEED) {
    hipMemsetAsync(d_out, 0, (size_t)out_size * 4, stream);
    return;
  }

  char* ws = (char*)d_ws;
  __bf16* wp0  = (__bf16*)(ws + OFF_WP0);
  __bf16* wp1  = (__bf16*)(ws + OFF_WP1);
  __bf16* wfc2 = (__bf16*)(ws + OFF_WFC);

  pack_w0<<<160, 256, 0, stream>>>(Wx0, Wh0, wp0);
  pack_w1<<<864, 256, 0, stream>>>(Wx1, Wh1, wp1);
  pack_wfc<<<2688, 256, 0, stream>>>(fc1w, wfc2);

  convlstm_persistent<<<2048, 256, 0, stream>>>(
      input, x_ex, wp0, wp1, wfc2, bx0, bx1, Wc0, Wc1, fc1b, exw, exb,
      (float*)d_out);
}

// Round 10
// 2870.434 us; speedup vs baseline: 1.9439x; 1.0031x over previous
//
#include <hip/hip_runtime.h>
#include <math.h>

// ConvLSTM encoder, MI355X. Batch-persistent: one block per batch element,
// 256 threads (4 waves), 1 block/CU (LDS 140 KB). All state on-chip:
// h0/h1 bf16 ping-pong in LDS, c0 fp32 in LDS, c1 fp32 in registers.
// Convs = MFMA GEMMs (M=pixels, N=gates*ch, K=im2col taps from LDS).
// R9 lessons: (a) dbuf register copies = ~56 cyc/K-step VALU -> manual
// unroll-2 ping-pong (no copies); (b) weight L2 streaming at per-CU BW
// ceiling -> layer-1 restructured 4->3 M-passes (acc [4][4]), cutting
// weight re-reads and K-steps by 25%.

typedef __bf16 bf16x8 __attribute__((ext_vector_type(8)));
typedef float  f32x4  __attribute__((ext_vector_type(4)));

__device__ __forceinline__ float sigm(float x)  { return 1.f / (1.f + __expf(-x)); }
__device__ __forceinline__ float ftanh(float x) { float e = __expf(2.f * x); return 1.f - 2.f / (e + 1.f); }

// ---------------- workspace layout (bytes) ----------------
#define OFF_WP0  ((size_t)0)          // [2][10][4][64][8] bf16 = 81,920
#define OFF_WP1  ((size_t)81920)      // [4][27][4][64][8] bf16 = 442,368
#define OFF_WFC  ((size_t)524288)     // [168][64][64] bf16 = 1,376,256
#define WS_NEED  ((size_t)1900544)

#define SH0N 9360    // 9*26*40 bf16 per h0 buffer
#define SH1N 16848   // 9*26*72 bf16 per h1 buffer

// ---------------- weight pack kernels (fragment-ordered) ----------------
// wp0f[((chh*10+s)*4+g)*512 + L*8 + e] = W0(n = g*32+chh*16+(L&15),
//   k = s*32+(L>>4)*8+e), K-order: k<32 im2col-x (k<18 real), k>=32 h-taps.
__global__ void pack_w0(const float* __restrict__ wx0, const float* __restrict__ wh0,
                        __bf16* __restrict__ dst) {
  int o = blockIdx.x * 256 + threadIdx.x;
  if (o >= 40960) return;
  int e = o & 7, L = (o >> 3) & 63;
  int idx = o >> 9;
  int g = idx & 3, sidx = idx >> 2;
  int s = sidx % 10, chh = sidx / 10;
  int n = g * 32 + chh * 16 + (L & 15);
  int k = s * 32 + (L >> 4) * 8 + e;
  float v = 0.f;
  if (k < 32) {
    if (k < 18) {
      int ky = k / 6, rem = k - ky * 6, kx = rem >> 1, ci = rem & 1;
      v = wx0[(n * 2 + ci) * 9 + ky * 3 + kx];
    }
  } else {
    int tk = k - 32, tap = tk >> 5, c = tk & 31;
    v = wh0[(n * 32 + c) * 9 + tap];
  }
  dst[o] = (__bf16)v;
}

// wp1f[((chq*27+s)*4+g)*512 + L*8 + e] = W1(n = g*64+chq*16+(L&15),
//   k = s*32+(L>>4)*8+e), K-order: k<288 x-conv taps, k>=288 h-taps.
__global__ void pack_w1(const float* __restrict__ wx1, const float* __restrict__ wh1,
                        __bf16* __restrict__ dst) {
  int o = blockIdx.x * 256 + threadIdx.x;
  if (o >= 221184) return;
  int e = o & 7, L = (o >> 3) & 63;
  int idx = o >> 9;
  int g = idx & 3, sidx = idx >> 2;
  int s = sidx % 27, chq = sidx / 27;
  int n = g * 64 + chq * 16 + (L & 15);
  int k = s * 32 + (L >> 4) * 8 + e;
  float v;
  if (k < 288) {
    int tap = k >> 5, c = k & 31;
    v = wx1[(n * 32 + c) * 9 + tap];
  } else {
    int tk = k - 288, s2 = tk >> 5, c = tk & 31, tap = s2 >> 1, hf = s2 & 1;
    v = wh1[(n * 64 + hf * 32 + c) * 9 + tap];
  }
  dst[o] = (__bf16)v;
}

// Wfc2[pix][ch][n] bf16 = fc1_w[n][ch*168+pix]
__global__ void pack_wfc(const float* __restrict__ w, __bf16* __restrict__ dst) {
  int o = blockIdx.x * 256 + threadIdx.x;
  if (o >= 168 * 64 * 64) return;
  int pix = o >> 12, ch = (o >> 6) & 63, n = o & 63;
  dst[o] = (__bf16)w[n * 10752 + ch * 168 + pix];
}

// ---------------- the persistent ConvLSTM kernel ----------------
__global__ __launch_bounds__(256) void convlstm_persistent(
    const float* __restrict__ input, const float* __restrict__ x_ex,
    const __bf16* __restrict__ wp0, const __bf16* __restrict__ wp1,
    const __bf16* __restrict__ wfc2,
    const float* __restrict__ bx0, const float* __restrict__ bx1,
    const float* __restrict__ wc0, const float* __restrict__ wc1,
    const float* __restrict__ fc1b,
    const float* __restrict__ exw, const float* __restrict__ exb,
    float* __restrict__ out)
{
  __shared__ __bf16 sh0[2 * SH0N];   // h0 ping-pong, [y][x][40] halo (37,440 B)
  __shared__ __bf16 sh1[2 * SH1N];   // h1 ping-pong, [y][x][72] halo (67,392 B)
  __shared__ __bf16 sx2[168 * 40];   // im2col x [pix][40], k<18 used (13,440 B)
  __shared__ float  c0l[168 * 33];   // c0 state fp32, [pix][33]      (22,176 B)

  const int b = blockIdx.x;
  const int t = threadIdx.x;
  const int w = t >> 6, L = t & 63;
  const int lo16 = L & 15, hi4 = L >> 4;

  // ---- zero LDS ----
  {
    int* p0 = (int*)sh0;
    for (int i = t; i < SH0N; i += 256) p0[i] = 0;
    int* p1 = (int*)sh1;
    for (int i = t; i < SH1N; i += 256) p1[i] = 0;
    int* p2 = (int*)sx2;
    for (int i = t; i < 168 * 40 / 2; i += 256) p2[i] = 0;
    for (int i = t; i < 168 * 33; i += 256) c0l[i] = 0.f;
  }
  __syncthreads();

  // ---- build im2col x2 (time-constant), [pix][40], k = ky*6+kx*2+cin ----
  if (t < 168) {
    int iy = t / 24, ix = t - iy * 24;
    __bf16* dst = sx2 + t * 40;
    for (int ky = 0; ky < 3; ++ky) {
      int y = iy + ky - 1;
      if (y < 0 || y >= 7) continue;
      for (int kx = 0; kx < 3; ++kx) {
        int x = ix + kx - 1;
        if (x < 0 || x >= 24) continue;
        int k0 = ky * 6 + kx * 2;
        dst[k0 + 0] = (__bf16)input[((b * 2 + 0) * 7 + y) * 24 + x];
        dst[k0 + 1] = (__bf16)input[((b * 2 + 1) * 7 + y) * 24 + x];
      }
    }
  }

  // ---- per-wave / per-lane constants ----
  const int mh = w >> 1, chh = w & 1;
  const int ch0 = chh * 16 + lo16;     // layer-0 channel (0..31)
  const int ch1 = w * 16 + lo16;       // layer-1 channel (0..63)

  const __bf16* w0f = wp0 + chh * 20480 + L * 8;   // + (s*4+g)*512
  const __bf16* w1f = wp1 + w * 55296 + L * 8;     // + (s*4+g)*512

  const float bi0 = bx0[ch0], bf0 = bx0[32 + ch0];
  const float bg0 = bx0[64 + ch0], bo0 = bx0[96 + ch0];
  const float bi1 = bx1[ch1], bf1 = bx1[64 + ch1];
  const float bg1 = bx1[128 + ch1], bo1 = bx1[192 + ch1];

  float c1r[3][4][4];
#pragma unroll
  for (int p = 0; p < 3; ++p)
#pragma unroll
    for (int j = 0; j < 4; ++j)
#pragma unroll
      for (int r = 0; r < 4; ++r) c1r[p][j][r] = 0.f;

  __syncthreads();   // x2 + zeroed state visible

#pragma unroll 1
  for (int st = 0; st < 7; ++st) {
    const __bf16* h0r = sh0 + (st & 1) * SH0N;
    __bf16*       h0w = sh0 + ((st + 1) & 1) * SH0N;
    const __bf16* h1r = sh1 + (st & 1) * SH1N;
    __bf16*       h1w = sh1 + ((st + 1) & 1) * SH1N;

    // ================= layer 0: 2 M-passes, unroll-2 ping-pong =============
#pragma unroll 1
    for (int q = 0; q < 2; ++q) {
      const int tb = mh * 6 + q * 3;               // first tile of this pass
      const int ntq = (mh == 1 && q == 1) ? 2 : 3; // tile 11 all-dummy
      int b0h[3], b0x[3];
#pragma unroll
      for (int j = 0; j < 3; ++j) {
        int pr = (tb + j) * 16 + lo16;
        if (pr > 167) pr = 167;
        int iy = pr / 24, ix = pr - iy * 24;
        b0h[j] = (iy * 26 + ix) * 40;
        b0x[j] = pr * 40 + hi4 * 8;
      }
      f32x4 a0[4][3];
#pragma unroll
      for (int g = 0; g < 4; ++g)
#pragma unroll
        for (int j = 0; j < 3; ++j) a0[g][j] = (f32x4){0.f, 0.f, 0.f, 0.f};

      auto loadA0 = [&](int s, bf16x8* af) {
        if (s == 0) {
#pragma unroll
          for (int j = 0; j < 3; ++j) af[j] = *(const bf16x8*)(sx2 + b0x[j]);
        } else {
          int tap = s - 1, ky = tap / 3, kx = tap - ky * 3;
          int toff = (ky * 26 + kx) * 40 + hi4 * 8;
#pragma unroll
          for (int j = 0; j < 3; ++j) af[j] = *(const bf16x8*)(h0r + b0h[j] + toff);
        }
      };
      auto loadB0 = [&](int s, bf16x8* bc) {
#pragma unroll
        for (int g = 0; g < 4; ++g)
          bc[g] = *(const bf16x8*)(w0f + (s * 4 + g) * 512);
      };
      auto mfma0 = [&](bf16x8* af, bf16x8* bc) {
#pragma unroll
        for (int j = 0; j < 3; ++j)
#pragma unroll
          for (int g = 0; g < 4; ++g)
            a0[g][j] = __builtin_amdgcn_mfma_f32_16x16x32_bf16(af[j], bc[g], a0[g][j], 0, 0, 0);
      };

      bf16x8 afA[3], afB[3], bcA[4], bcB[4];
      loadA0(0, afA); loadB0(0, bcA);
      loadA0(1, afB); loadB0(1, bcB);
#pragma unroll 1
      for (int s = 0; s < 10; s += 2) {
        mfma0(afA, bcA);
        int s2 = (s + 2 < 10) ? s + 2 : 9;
        loadA0(s2, afA); loadB0(s2, bcA);
        mfma0(afB, bcB);
        int s3 = (s + 3 < 10) ? s + 3 : 9;
        loadA0(s3, afB); loadB0(s3, bcB);
      }

      // epilogue: lane owns (pix = (tb+j)*16 + hi4*4 + r, ch0); c0 in LDS
#pragma unroll
      for (int j = 0; j < 3; ++j) {
        if (j < ntq) {
#pragma unroll
          for (int r = 0; r < 4; ++r) {
            int p = (tb + j) * 16 + hi4 * 4 + r;
            if (p < 168) {
              float c = c0l[p * 33 + ch0];
              float gi = a0[0][j][r] + bi0;
              float gf = a0[1][j][r] + bf0;
              float gc = a0[2][j][r] + bg0;
              float go = a0[3][j][r] + bo0;
              float wci = wc0[ch0 * 168 + p];
              float wcf = wc0[5376 + ch0 * 168 + p];
              float wco = wc0[10752 + ch0 * 168 + p];
              float ig = sigm(gi + c * wci);
              float fg = sigm(gf + c * wcf);
              float cn = fg * c + ig * ftanh(gc);
              float og = sigm(go + cn * wco);
              float hn = og * ftanh(cn);
              c0l[p * 33 + ch0] = cn;
              int iy = p / 24, ix = p - iy * 24;
              h0w[((iy + 1) * 26 + ix + 1) * 40 + ch0] = (__bf16)hn;
            }
          }
        }
      }
    }
    __syncthreads();   // h0(t) visible (and all h0(t-1)/x2 reads done)

    // ======== layer 1: 3 M-passes x 4 tiles, unroll-2 ping-pong ===========
#pragma unroll
    for (int p3 = 0; p3 < 3; ++p3) {
      const int ntp = (p3 == 2) ? 3 : 4;           // tile 11 all-dummy
      int b1h0[4], b1h1[4];
#pragma unroll
      for (int j = 0; j < 4; ++j) {
        int pr = (p3 * 4 + j) * 16 + lo16;
        if (pr > 167) pr = 167;
        int iy = pr / 24, ix = pr - iy * 24;
        b1h0[j] = (iy * 26 + ix) * 40;
        b1h1[j] = (iy * 26 + ix) * 72;
      }
      f32x4 a1[4][4];
#pragma unroll
      for (int g = 0; g < 4; ++g)
#pragma unroll
        for (int j = 0; j < 4; ++j) a1[g][j] = (f32x4){0.f, 0.f, 0.f, 0.f};

      auto loadA1 = [&](int s, bf16x8* af) {
        if (s < 9) {
          int ky = s / 3, kx = s - ky * 3;
          int toff = (ky * 26 + kx) * 40 + hi4 * 8;
#pragma unroll
          for (int j = 0; j < 4; ++j) af[j] = *(const bf16x8*)(h0w + b1h0[j] + toff);
        } else {
          int t2 = s - 9, tap = t2 >> 1, hf = t2 & 1;
          int ky = tap / 3, kx = tap - ky * 3;
          int toff = (ky * 26 + kx) * 72 + hf * 32 + hi4 * 8;
#pragma unroll
          for (int j = 0; j < 4; ++j) af[j] = *(const bf16x8*)(h1r + b1h1[j] + toff);
        }
      };
      auto loadB1 = [&](int s, bf16x8* bc) {
#pragma unroll
        for (int g = 0; g < 4; ++g)
          bc[g] = *(const bf16x8*)(w1f + (s * 4 + g) * 512);
      };
      auto mfma1 = [&](bf16x8* af, bf16x8* bc) {
#pragma unroll
        for (int j = 0; j < 4; ++j) {
          if (j < ntp) {
#pragma unroll
            for (int g = 0; g < 4; ++g)
              a1[g][j] = __builtin_amdgcn_mfma_f32_16x16x32_bf16(af[j], bc[g], a1[g][j], 0, 0, 0);
          }
        }
      };

      bf16x8 afA[4], afB[4], bcA[4], bcB[4];
      loadA1(0, afA); loadB1(0, bcA);
      loadA1(1, afB); loadB1(1, bcB);
#pragma unroll 1
      for (int s = 0; s < 26; s += 2) {
        mfma1(afA, bcA);
        int s2 = (s + 2 < 27) ? s + 2 : 26;
        loadA1(s2, afA); loadB1(s2, bcA);
        mfma1(afB, bcB);
        int s3 = (s + 3 < 27) ? s + 3 : 26;
        loadA1(s3, afB); loadB1(s3, bcB);
      }
      mfma1(afA, bcA);   // s = 26 tail

      // epilogue: lane owns (pix = (p3*4+j)*16 + hi4*4 + r, ch1); h -> h1w
#pragma unroll
      for (int j = 0; j < 4; ++j) {
        if (j < ntp) {
#pragma unroll
          for (int r = 0; r < 4; ++r) {
            int p = (p3 * 4 + j) * 16 + hi4 * 4 + r;
            if (p < 168) {
              float c = c1r[p3][j][r];
              float gi = a1[0][j][r] + bi1;
              float gf = a1[1][j][r] + bf1;
              float gc = a1[2][j][r] + bg1;
              float go = a1[3][j][r] + bo1;
              float wci = wc1[ch1 * 168 + p];
              float wcf = wc1[10752 + ch1 * 168 + p];
              float wco = wc1[21504 + ch1 * 168 + p];
              float ig = sigm(gi + c * wci);
              float fg = sigm(gf + c * wcf);
              float cn = fg * c + ig * ftanh(gc);
              float og = sigm(go + cn * wco);
              float hn = og * ftanh(cn);
              c1r[p3][j][r] = cn;
              int iy = p / 24, ix = p - iy * 24;
              h1w[((iy + 1) * 26 + ix + 1) * 72 + ch1] = (__bf16)hn;
            }
          }
        }
      }
    }
    __syncthreads();   // h1(t) visible (and all h1(t-1)/h0(t) reads done)
  }

  // ================= FC heads (h1 final in sh1 buffer 1) =================
  {
    const __bf16* h1f = sh1 + SH1N;      // (st=6 wrote buffer (6+1)&1 = 1)
    const int o = t & 3, pg = t >> 2;    // o: 16 n's (o*16..); pg 0..63
    float part[16];
#pragma unroll
    for (int q = 0; q < 16; ++q) part[q] = 0.f;
#pragma unroll 1
    for (int jj = 0; jj < 3; ++jj) {
      int p = pg + 64 * jj;
      if (p < 168) {
        int iy = p / 24, ix = p - iy * 24;
        const __bf16* hrow = h1f + ((iy + 1) * 26 + ix + 1) * 72;
        const __bf16* wrow = wfc2 + (size_t)p * 4096 + o * 16;
        for (int ch = 0; ch < 64; ++ch) {
          float hv = (float)hrow[ch];
          bf16x8 wv0 = *(const bf16x8*)(wrow + ch * 64);
          bf16x8 wv1 = *(const bf16x8*)(wrow + ch * 64 + 8);
#pragma unroll
          for (int q = 0; q < 8; ++q) {
            part[q] += hv * (float)wv0[q];
            part[8 + q] += hv * (float)wv1[q];
          }
        }
      }
    }
    float* sacc = c0l;   // c0 state dead after last step; 16 KB needed
    __syncthreads();
#pragma unroll
    for (int q = 0; q < 16; ++q) sacc[pg * 64 + o * 16 + q] = part[q];
    __syncthreads();
    if (t < 64) {
      float s = fc1b[t];
      for (int pg2 = 0; pg2 < 64; ++pg2) s += sacc[pg2 * 64 + t];
      out[(size_t)b * 128 + t] = fmaxf(s, 0.f);
    } else if (t < 128) {
      int j = t - 64;
      float s = exb[j];
      for (int k = 0; k < 24; ++k) s += x_ex[b * 24 + k] * exw[j * 24 + k];
      out[(size_t)b * 128 + 64 + j] = fmaxf(s, 0.f);
    }
  }
}

// ---------------- launcher ----------------
extern "C" void kernel_launch(void* const* d_in, const int* in_sizes, int n_in,
                              void* d_out, int out_size, void* d_ws, size_t ws_size,
                              hipStream_t stream) {
  const float* input = (const float*)d_in[0];
  const float* x_ex  = (const float*)d_in[1];
  const float* Wx0   = (const float*)d_in[2];
  const float* bx0   = (const float*)d_in[3];
  const float* Wh0   = (const float*)d_in[4];
  const float* Wc0   = (const float*)d_in[5];
  const float* Wx1   = (const float*)d_in[6];
  const float* bx1   = (const float*)d_in[7];
  const float* Wh1   = (const float*)d_in[8];
  const float* Wc1   = (const float*)d_in[9];
  const float* fc1w  = (const float*)d_in[10];
  const float* fc1b  = (const float*)d_in[11];
  const float* exw   = (const float*)d_in[12];
  const float* exb   = (const float*)d_in[13];
  (void)in_sizes; (void)n_in;

  if (ws_size < WS_NEED) {
    hipMemsetAsync(d_out, 0, (size_t)out_size * 4, stream);
    return;
  }

  char* ws = (char*)d_ws;
  __bf16* wp0  = (__bf16*)(ws + OFF_WP0);
  __bf16* wp1  = (__bf16*)(ws + OFF_WP1);
  __bf16* wfc2 = (__bf16*)(ws + OFF_WFC);

  pack_w0<<<160, 256, 0, stream>>>(Wx0, Wh0, wp0);
  pack_w1<<<864, 256, 0, stream>>>(Wx1, Wh1, wp1);
  pack_wfc<<<2688, 256, 0, stream>>>(fc1w, wfc2);

  convlstm_persistent<<<2048, 256, 0, stream>>>(
      input, x_ex, wp0, wp1, wfc2, bx0, bx1, Wc0, Wc1, fc1b, exw, exb,
      (float*)d_out);
}